// Round 11
// baseline (99.134 us; speedup 1.0000x reference)
//
#include <hip/hip_runtime.h>
#include <hip/hip_bf16.h>

typedef __bf16 bf16_t;
typedef __bf16 bf16x8 __attribute__((ext_vector_type(8)));
typedef __bf16 bf16x4 __attribute__((ext_vector_type(4)));
typedef float  f32x4  __attribute__((ext_vector_type(4)));

#define B_   2
#define S_   2048
#define D_   1024
#define H_   16
#define HD_  64
#define HW   32
#define SCALE_ 0.125f

__device__ __forceinline__ void gl_lds16(const bf16_t* g, bf16_t* l) {
  __builtin_amdgcn_global_load_lds(
      (const __attribute__((address_space(1))) void*)g,
      (__attribute__((address_space(3))) void*)l, 16, 0, 0);
}

// ------------- fused converts: x fp32->bf16 (blocks 0..2047), W transpose (2048..3071)
__global__ __launch_bounds__(256) void k_conv(const float* __restrict__ X,
                                              const float* __restrict__ W0,
                                              const float* __restrict__ W1,
                                              const float* __restrict__ W2,
                                              const float* __restrict__ W3,
                                              bf16_t* __restrict__ Xb,
                                              bf16_t* __restrict__ Wt) {
  __shared__ bf16_t t[64][72];
  int bid = blockIdx.x;
  int tid = threadIdx.x;
  if (bid < 2048) {
    int i = bid * 256 + tid;
    const float4 a = ((const float4*)X)[i * 2];
    const float4 b = ((const float4*)X)[i * 2 + 1];
    bf16x8 r;
    r[0] = (bf16_t)a.x; r[1] = (bf16_t)a.y; r[2] = (bf16_t)a.z; r[3] = (bf16_t)a.w;
    r[4] = (bf16_t)b.x; r[5] = (bf16_t)b.y; r[6] = (bf16_t)b.z; r[7] = (bf16_t)b.w;
    ((bf16x8*)Xb)[i] = r;
    return;
  }
  int wb = bid - 2048;
  int wsel = wb >> 8;
  const float* W = (wsel == 0) ? W0 : (wsel == 1) ? W1 : (wsel == 2) ? W2 : W3;
  bf16_t* dst = Wt + (size_t)wsel * D_ * D_;
  int tile = wb & 255;
  int k0 = (tile >> 4) * 64, n0 = (tile & 15) * 64;
  int r = tid >> 4, c4 = (tid & 15) * 4;
#pragma unroll
  for (int i = 0; i < 4; ++i) {
    int row = i * 16 + r;
    float4 v = *(const float4*)(W + (size_t)(k0 + row) * D_ + n0 + c4);
    t[row][c4 + 0] = (bf16_t)v.x;
    t[row][c4 + 1] = (bf16_t)v.y;
    t[row][c4 + 2] = (bf16_t)v.z;
    t[row][c4 + 3] = (bf16_t)v.w;
  }
  __syncthreads();
#pragma unroll
  for (int i = 0; i < 4; ++i) {
    int row = i * 16 + r;
    bf16x4 o;
    o[0] = t[c4 + 0][row];
    o[1] = t[c4 + 1][row];
    o[2] = t[c4 + 2][row];
    o[3] = t[c4 + 3][row];
    *(bf16x4*)(dst + (size_t)(n0 + row) * D_ + k0 + c4) = o;
  }
}

// ---- QKV GEMM: 64x128 tile, BK=32, 2-barrier gl_lds loop, 6 blocks/CU ----
// waves 1x4 over (64,128): wave tile 64x32 -> 4x2 frags.
// staging: 12 chunks (A0..A3, B0..B7) of 16rows x 32cols; wave w stages 3w..3w+2.
__global__ __launch_bounds__(256) void k_gemm_qkv(const bf16_t* __restrict__ X,
                                                  const bf16_t* __restrict__ Wt,
                                                  bf16_t* __restrict__ Q,
                                                  bf16_t* __restrict__ K,
                                                  bf16_t* __restrict__ V) {
  __shared__ bf16_t sA[64 * 32];
  __shared__ bf16_t sB[128 * 32];
  int bid = blockIdx.x;
  int mt = bid & 63, nt = bid >> 6;   // 64 x 24; XCD = mt%8 spreads A panels
  int wsel = nt >> 3;
  int n0 = (nt & 7) * 128, m0 = mt * 64;
  const bf16_t* Wp = Wt + (size_t)wsel * D_ * D_;
  int tid = threadIdx.x, lane = tid & 63, wave = tid >> 6;
  int wc = wave * 32;
  int crow = lane >> 2, ccol = (lane & 3) * 8;
  // 3 staging chunks for this wave
  const bf16_t* gsrc0; bf16_t* ldst0;
  const bf16_t* gsrc1; bf16_t* ldst1;
  const bf16_t* gsrc2; bf16_t* ldst2;
#pragma unroll
  for (int j = 0; j < 3; ++j) {
    int c = wave * 3 + j;
    const bf16_t* g; bf16_t* l;
    if (c < 4) {
      g = X + (size_t)(m0 + c * 16 + crow) * D_ + ccol;
      l = sA + c * 512;
    } else {
      g = Wp + (size_t)(n0 + (c - 4) * 16 + crow) * D_ + ccol;
      l = sB + (c - 4) * 512;
    }
    if (j == 0) { gsrc0 = g; ldst0 = l; }
    else if (j == 1) { gsrc1 = g; ldst1 = l; }
    else { gsrc2 = g; ldst2 = l; }
  }
  f32x4 acc[4][2] = {};
  int kq = (lane >> 4) * 8, rl = lane & 15, hi = lane >> 4;
  for (int kt = 0; kt < D_; kt += 32) {
    __syncthreads();
    gl_lds16(gsrc0 + kt, ldst0);
    gl_lds16(gsrc1 + kt, ldst1);
    gl_lds16(gsrc2 + kt, ldst2);
    __syncthreads();
    bf16x8 af[4], bfr[2];
#pragma unroll
    for (int m = 0; m < 4; ++m)
      af[m] = *(const bf16x8*)&sA[(m * 16 + rl) * 32 + kq];
#pragma unroll
    for (int n = 0; n < 2; ++n)
      bfr[n] = *(const bf16x8*)&sB[(wc + n * 16 + rl) * 32 + kq];
#pragma unroll
    for (int m = 0; m < 4; ++m)
#pragma unroll
      for (int n = 0; n < 2; ++n)
        acc[m][n] = __builtin_amdgcn_mfma_f32_16x16x32_bf16(af[m], bfr[n], acc[m][n], 0, 0, 0);
  }
  float qscale = (wsel == 0) ? SCALE_ : 1.0f;
#pragma unroll
  for (int m = 0; m < 4; ++m) {
#pragma unroll
    for (int n = 0; n < 2; ++n) {
#pragma unroll
      for (int r = 0; r < 4; ++r) {
        int gm = m0 + m * 16 + hi * 4 + r;
        int gn = n0 + wc + n * 16 + rl;
        int b = gm >> 11, s = gm & 2047;
        int h = gn >> 6, hd = gn & 63;
        bf16_t val = (bf16_t)(acc[m][n][r] * qscale);
        if (wsel == 0)
          Q[(((size_t)(b * H_ + h)) * S_ + s) * HD_ + hd] = val;
        else if (wsel == 1)
          K[(((size_t)(b * H_ + h)) * S_ + s) * HD_ + hd] = val;
        else
          V[(((size_t)(b * H_ + h)) * HD_ + hd) * S_ + s] = val;  // transposed
      }
    }
  }
}

// ---- out GEMM: 64x128 tile, same structure, 512 blocks (2/CU) ----
__global__ __launch_bounds__(256) void k_gemm_out(const bf16_t* __restrict__ A,
                                                  const bf16_t* __restrict__ Wp,
                                                  const float* __restrict__ bo,
                                                  float* __restrict__ out) {
  __shared__ bf16_t sA[64 * 32];
  __shared__ bf16_t sB[128 * 32];
  int bid = blockIdx.x;
  int mt = bid & 63, nt = bid >> 6;   // 64 x 8
  int n0 = nt * 128, m0 = mt * 64;
  int tid = threadIdx.x, lane = tid & 63, wave = tid >> 6;
  int wc = wave * 32;
  int crow = lane >> 2, ccol = (lane & 3) * 8;
  const bf16_t* gsrc0; bf16_t* ldst0;
  const bf16_t* gsrc1; bf16_t* ldst1;
  const bf16_t* gsrc2; bf16_t* ldst2;
#pragma unroll
  for (int j = 0; j < 3; ++j) {
    int c = wave * 3 + j;
    const bf16_t* g; bf16_t* l;
    if (c < 4) {
      g = A + (size_t)(m0 + c * 16 + crow) * D_ + ccol;
      l = sA + c * 512;
    } else {
      g = Wp + (size_t)(n0 + (c - 4) * 16 + crow) * D_ + ccol;
      l = sB + (c - 4) * 512;
    }
    if (j == 0) { gsrc0 = g; ldst0 = l; }
    else if (j == 1) { gsrc1 = g; ldst1 = l; }
    else { gsrc2 = g; ldst2 = l; }
  }
  f32x4 acc[4][2] = {};
  int kq = (lane >> 4) * 8, rl = lane & 15, hi = lane >> 4;
  for (int kt = 0; kt < D_; kt += 32) {
    __syncthreads();
    gl_lds16(gsrc0 + kt, ldst0);
    gl_lds16(gsrc1 + kt, ldst1);
    gl_lds16(gsrc2 + kt, ldst2);
    __syncthreads();
    bf16x8 af[4], bfr[2];
#pragma unroll
    for (int m = 0; m < 4; ++m)
      af[m] = *(const bf16x8*)&sA[(m * 16 + rl) * 32 + kq];
#pragma unroll
    for (int n = 0; n < 2; ++n)
      bfr[n] = *(const bf16x8*)&sB[(wc + n * 16 + rl) * 32 + kq];
#pragma unroll
    for (int m = 0; m < 4; ++m)
#pragma unroll
      for (int n = 0; n < 2; ++n)
        acc[m][n] = __builtin_amdgcn_mfma_f32_16x16x32_bf16(af[m], bfr[n], acc[m][n], 0, 0, 0);
  }
#pragma unroll
  for (int m = 0; m < 4; ++m) {
#pragma unroll
    for (int n = 0; n < 2; ++n) {
#pragma unroll
      for (int r = 0; r < 4; ++r) {
        int gm = m0 + m * 16 + hi * 4 + r;
        int gn = n0 + wc + n * 16 + rl;
        out[(size_t)gm * D_ + gn] = acc[m][n][r] + bo[gn];
      }
    }
  }
}

// ---------------- MFMA local causal attention: Q direct from global, 39KB LDS ----
#define QB 64
#define KW 112
#define KLP 68
#define VTP 116

__global__ __launch_bounds__(256) void k_attn(const bf16_t* __restrict__ Q,
                                              const bf16_t* __restrict__ K,
                                              const bf16_t* __restrict__ Vt,
                                              bf16_t* __restrict__ O) {
  __shared__ bf16_t sK[KW][KLP];
  __shared__ bf16_t sV[HD_][VTP];
  __shared__ bf16_t sP[4][16][KLP];
  int bid = blockIdx.x;
  int qb = bid & 31, bh = bid >> 5;
  int q0 = qb * QB;
  const bf16_t* Kp = K + (size_t)bh * S_ * HD_;
  const bf16_t* Vp = Vt + (size_t)bh * HD_ * S_;
  const bf16_t* Qp = Q + (size_t)bh * S_ * HD_;
  int tid = threadIdx.x;
  int lane = tid & 63, wave = tid >> 6;
  int rl = lane & 15, hi = lane >> 4;
  int wk0b = q0 - HW;
  // Q fragments straight from global (no LDS)
  bf16x8 qf0 = *(const bf16x8*)(Qp + (size_t)(q0 + wave * 16 + rl) * HD_ + hi * 8);
  bf16x8 qf1 = *(const bf16x8*)(Qp + (size_t)(q0 + wave * 16 + rl) * HD_ + 32 + hi * 8);
  for (int idx = tid; idx < KW * 8; idx += 256) {
    int row = idx >> 3, c8 = (idx & 7) * 8;
    int kg = wk0b + row;
    kg = kg < 0 ? 0 : (kg > S_ - 1 ? S_ - 1 : kg);
    *(bf16x8*)&sK[row][c8] = *(const bf16x8*)(Kp + (size_t)kg * HD_ + c8);
  }
  for (int idx = tid; idx < HD_ * 14; idx += 256) {
    int row = idx / 14, c8 = (idx % 14) * 8;
    int ks = wk0b + c8;
    ks = ks < 0 ? 0 : (ks > S_ - 8 ? S_ - 8 : ks);
    *(bf16x8*)&sV[row][c8] = *(const bf16x8*)(Vp + (size_t)row * S_ + ks);
  }
  __syncthreads();
  int wko = wave * 16;
  f32x4 accs[4] = {};
#pragma unroll
  for (int kb = 0; kb < 4; ++kb) {
    bf16x8 kf = *(const bf16x8*)&sK[wko + kb * 16 + rl][hi * 8];
    accs[kb] = __builtin_amdgcn_mfma_f32_16x16x32_bf16(kf, qf0, accs[kb], 0, 0, 0);
  }
#pragma unroll
  for (int kb = 0; kb < 4; ++kb) {
    bf16x8 kf = *(const bf16x8*)&sK[wko + kb * 16 + rl][32 + hi * 8];
    accs[kb] = __builtin_amdgcn_mfma_f32_16x16x32_bf16(kf, qf1, accs[kb], 0, 0, 0);
  }
  float p[4][4];
  float mx = -1e30f;
#pragma unroll
  for (int kb = 0; kb < 4; ++kb) {
#pragma unroll
    for (int r = 0; r < 4; ++r) {
      int kl = kb * 16 + hi * 4 + r;
      bool valid = (kl >= rl) && (kl <= rl + HW) && (wk0b + wko + kl >= 0);
      float s = valid ? accs[kb][r] : -1e30f;
      p[kb][r] = s;
      mx = fmaxf(mx, s);
    }
  }
  mx = fmaxf(mx, __shfl_xor(mx, 16));
  mx = fmaxf(mx, __shfl_xor(mx, 32));
  float sum = 0.f;
#pragma unroll
  for (int kb = 0; kb < 4; ++kb)
#pragma unroll
    for (int r = 0; r < 4; ++r) {
      p[kb][r] = __expf(p[kb][r] - mx);
      sum += p[kb][r];
    }
  sum += __shfl_xor(sum, 16);
  sum += __shfl_xor(sum, 32);
  float inv = 1.f / sum;
#pragma unroll
  for (int kb = 0; kb < 4; ++kb) {
    bf16x4 pv;
#pragma unroll
    for (int r = 0; r < 4; ++r) pv[r] = (bf16_t)(p[kb][r] * inv);
    *(bf16x4*)&sP[wave][rl][kb * 16 + hi * 4] = pv;
  }
  f32x4 acco[4] = {};
#pragma unroll
  for (int ks = 0; ks < 2; ++ks) {
    bf16x8 aP = *(const bf16x8*)&sP[wave][rl][ks * 32 + hi * 8];
#pragma unroll
    for (int n = 0; n < 4; ++n) {
      bf16x8 bV = *(const bf16x8*)&sV[n * 16 + rl][wko + ks * 32 + hi * 8];
      acco[n] = __builtin_amdgcn_mfma_f32_16x16x32_bf16(aP, bV, acco[n], 0, 0, 0);
    }
  }
  int b = bh >> 4, h = bh & 15;
#pragma unroll
  for (int n = 0; n < 4; ++n) {
#pragma unroll
    for (int r = 0; r < 4; ++r) {
      int qgl = q0 + wave * 16 + hi * 4 + r;
      int d = n * 16 + rl;
      O[((size_t)(b * S_ + qgl)) * D_ + h * HD_ + d] = (bf16_t)acco[n][r];
    }
  }
}

extern "C" void kernel_launch(void* const* d_in, const int* in_sizes, int n_in,
                              void* d_out, int out_size, void* d_ws, size_t ws_size,
                              hipStream_t stream) {
  const float* x  = (const float*)d_in[0];
  const float* Wq = (const float*)d_in[1];
  const float* Wk = (const float*)d_in[2];
  const float* Wv = (const float*)d_in[3];
  const float* Wo = (const float*)d_in[4];
  const float* bo = (const float*)d_in[5];
  float* out = (float*)d_out;
  char* ws = (char*)d_ws;
  bf16_t* xb = (bf16_t*)(ws);                       // 8 MB
  bf16_t* wt = (bf16_t*)(ws + (size_t)(8 << 20));   // 8 MB [4][1024][1024]
  bf16_t* qb = (bf16_t*)(ws + (size_t)(16 << 20));  // 8 MB [bh][s][64]
  bf16_t* kb = (bf16_t*)(ws + (size_t)(24 << 20));  // 8 MB [bh][s][64]
  bf16_t* vb = (bf16_t*)(ws + (size_t)(32 << 20));  // 8 MB [bh][64][s] (transposed)
  bf16_t* ob = (bf16_t*)(ws + (size_t)(40 << 20));  // 8 MB [b][s][1024]

  hipLaunchKernelGGL(k_conv, dim3(3072), dim3(256), 0, stream,
                     x, Wq, Wk, Wv, Wo, xb, wt);
  hipLaunchKernelGGL(k_gemm_qkv, dim3(1536), dim3(256), 0, stream, xb, wt, qb, kb, vb);
  hipLaunchKernelGGL(k_attn, dim3(1024), dim3(256), 0, stream, qb, kb, vb, ob);
  hipLaunchKernelGGL(k_gemm_out, dim3(512), dim3(256), 0, stream,
                     ob, wt + (size_t)3 * D_ * D_, bo, out);
}

// Round 12
// 81.503 us; speedup vs baseline: 1.2163x; 1.2163x over previous
//
#include <hip/hip_runtime.h>
#include <hip/hip_bf16.h>

typedef __bf16 bf16_t;
typedef __bf16 bf16x8 __attribute__((ext_vector_type(8)));
typedef __bf16 bf16x4 __attribute__((ext_vector_type(4)));
typedef float  f32x4  __attribute__((ext_vector_type(4)));

#define B_   2
#define S_   2048
#define D_   1024
#define H_   16
#define HD_  64
#define HW   32
#define SCALE_ 0.125f

__device__ __forceinline__ void gl_lds16(const bf16_t* g, bf16_t* l) {
  __builtin_amdgcn_global_load_lds(
      (const __attribute__((address_space(1))) void*)g,
      (__attribute__((address_space(3))) void*)l, 16, 0, 0);
}

// ------------- fused converts: x fp32->bf16 (blocks 0..2047), W transpose (2048..3071)
__global__ __launch_bounds__(256) void k_conv(const float* __restrict__ X,
                                              const float* __restrict__ W0,
                                              const float* __restrict__ W1,
                                              const float* __restrict__ W2,
                                              const float* __restrict__ W3,
                                              bf16_t* __restrict__ Xb,
                                              bf16_t* __restrict__ Wt) {
  __shared__ bf16_t t[64][72];
  int bid = blockIdx.x;
  int tid = threadIdx.x;
  if (bid < 2048) {
    int i = bid * 256 + tid;
    const float4 a = ((const float4*)X)[i * 2];
    const float4 b = ((const float4*)X)[i * 2 + 1];
    bf16x8 r;
    r[0] = (bf16_t)a.x; r[1] = (bf16_t)a.y; r[2] = (bf16_t)a.z; r[3] = (bf16_t)a.w;
    r[4] = (bf16_t)b.x; r[5] = (bf16_t)b.y; r[6] = (bf16_t)b.z; r[7] = (bf16_t)b.w;
    ((bf16x8*)Xb)[i] = r;
    return;
  }
  int wb = bid - 2048;
  int wsel = wb >> 8;
  const float* W = (wsel == 0) ? W0 : (wsel == 1) ? W1 : (wsel == 2) ? W2 : W3;
  bf16_t* dst = Wt + (size_t)wsel * D_ * D_;
  int tile = wb & 255;
  int k0 = (tile >> 4) * 64, n0 = (tile & 15) * 64;
  int r = tid >> 4, c4 = (tid & 15) * 4;
#pragma unroll
  for (int i = 0; i < 4; ++i) {
    int row = i * 16 + r;
    float4 v = *(const float4*)(W + (size_t)(k0 + row) * D_ + n0 + c4);
    t[row][c4 + 0] = (bf16_t)v.x;
    t[row][c4 + 1] = (bf16_t)v.y;
    t[row][c4 + 2] = (bf16_t)v.z;
    t[row][c4 + 3] = (bf16_t)v.w;
  }
  __syncthreads();
#pragma unroll
  for (int i = 0; i < 4; ++i) {
    int row = i * 16 + r;
    bf16x4 o;
    o[0] = t[c4 + 0][row];
    o[1] = t[c4 + 1][row];
    o[2] = t[c4 + 2][row];
    o[3] = t[c4 + 3][row];
    *(bf16x4*)(dst + (size_t)(n0 + row) * D_ + k0 + c4) = o;
  }
}

// ---- QKV GEMM: round-6 exact. 128x128, BK=32, 2-barrier gl_lds loop ----
__global__ __launch_bounds__(256) void k_gemm_qkv(const bf16_t* __restrict__ X,
                                                  const bf16_t* __restrict__ Wt,
                                                  bf16_t* __restrict__ Q,
                                                  bf16_t* __restrict__ K,
                                                  bf16_t* __restrict__ V) {
  __shared__ bf16_t sA[128 * 32];
  __shared__ bf16_t sB[128 * 32];
  int bid = blockIdx.x;
  int mt = bid & 31, nt = bid >> 5;   // XCD = mt%8: 1MB A + 2MB B per XCD L2
  int wsel = nt >> 3;
  int n0 = (nt & 7) * 128, m0 = mt * 128;
  const bf16_t* Wp = Wt + (size_t)wsel * D_ * D_;
  int tid = threadIdx.x, lane = tid & 63, wave = tid >> 6;
  int wr = (wave >> 1) * 64, wc = (wave & 1) * 64;
  int r0 = wave * 32 + (lane >> 2);
  int ce = (lane & 3) * 8;
  const bf16_t* gA0 = X + (size_t)(m0 + r0) * D_ + ce;
  const bf16_t* gB0 = Wp + (size_t)(n0 + r0) * D_ + ce;
  bf16_t* lA0 = sA + wave * 1024;
  bf16_t* lB0 = sB + wave * 1024;
  f32x4 acc[4][4] = {};
  int kq = (lane >> 4) * 8, rl = lane & 15;
  for (int kt = 0; kt < D_; kt += 32) {
    __syncthreads();
    gl_lds16(gA0 + kt, lA0);
    gl_lds16(gA0 + kt + (size_t)16 * D_, lA0 + 512);
    gl_lds16(gB0 + kt, lB0);
    gl_lds16(gB0 + kt + (size_t)16 * D_, lB0 + 512);
    __syncthreads();
    bf16x8 af[4], bfr[4];
#pragma unroll
    for (int m = 0; m < 4; ++m)
      af[m] = *(const bf16x8*)&sA[(wr + m * 16 + rl) * 32 + kq];
#pragma unroll
    for (int n = 0; n < 4; ++n)
      bfr[n] = *(const bf16x8*)&sB[(wc + n * 16 + rl) * 32 + kq];
#pragma unroll
    for (int m = 0; m < 4; ++m)
#pragma unroll
      for (int n = 0; n < 4; ++n)
        acc[m][n] = __builtin_amdgcn_mfma_f32_16x16x32_bf16(af[m], bfr[n], acc[m][n], 0, 0, 0);
  }
  float qscale = (wsel == 0) ? SCALE_ : 1.0f;
#pragma unroll
  for (int m = 0; m < 4; ++m) {
#pragma unroll
    for (int n = 0; n < 4; ++n) {
#pragma unroll
      for (int r = 0; r < 4; ++r) {
        int gm = m0 + wr + m * 16 + (lane >> 4) * 4 + r;
        int gn = n0 + wc + n * 16 + rl;
        int b = gm >> 11, s = gm & 2047;
        int h = gn >> 6, hd = gn & 63;
        bf16_t val = (bf16_t)(acc[m][n][r] * qscale);
        if (wsel == 0)
          Q[(((size_t)(b * H_ + h)) * S_ + s) * HD_ + hd] = val;
        else if (wsel == 1)
          K[(((size_t)(b * H_ + h)) * S_ + s) * HD_ + hd] = val;
        else
          V[(((size_t)(b * H_ + h)) * HD_ + hd) * S_ + s] = val;  // transposed
      }
    }
  }
}

// ---- out GEMM: 64x128 tile (r11 win: 2 blocks/CU vs 1), BK=32, 2-barrier ----
__global__ __launch_bounds__(256) void k_gemm_out(const bf16_t* __restrict__ A,
                                                  const bf16_t* __restrict__ Wp,
                                                  const float* __restrict__ bo,
                                                  float* __restrict__ out) {
  __shared__ bf16_t sA[64 * 32];
  __shared__ bf16_t sB[128 * 32];
  int bid = blockIdx.x;
  int mt = bid & 63, nt = bid >> 6;   // 64 x 8
  int n0 = nt * 128, m0 = mt * 64;
  int tid = threadIdx.x, lane = tid & 63, wave = tid >> 6;
  int wc = wave * 32;
  int crow = lane >> 2, ccol = (lane & 3) * 8;
  const bf16_t* gsrc0; bf16_t* ldst0;
  const bf16_t* gsrc1; bf16_t* ldst1;
  const bf16_t* gsrc2; bf16_t* ldst2;
#pragma unroll
  for (int j = 0; j < 3; ++j) {
    int c = wave * 3 + j;
    const bf16_t* g; bf16_t* l;
    if (c < 4) {
      g = A + (size_t)(m0 + c * 16 + crow) * D_ + ccol;
      l = sA + c * 512;
    } else {
      g = Wp + (size_t)(n0 + (c - 4) * 16 + crow) * D_ + ccol;
      l = sB + (c - 4) * 512;
    }
    if (j == 0) { gsrc0 = g; ldst0 = l; }
    else if (j == 1) { gsrc1 = g; ldst1 = l; }
    else { gsrc2 = g; ldst2 = l; }
  }
  f32x4 acc[4][2] = {};
  int kq = (lane >> 4) * 8, rl = lane & 15, hi = lane >> 4;
  for (int kt = 0; kt < D_; kt += 32) {
    __syncthreads();
    gl_lds16(gsrc0 + kt, ldst0);
    gl_lds16(gsrc1 + kt, ldst1);
    gl_lds16(gsrc2 + kt, ldst2);
    __syncthreads();
    bf16x8 af[4], bfr[2];
#pragma unroll
    for (int m = 0; m < 4; ++m)
      af[m] = *(const bf16x8*)&sA[(m * 16 + rl) * 32 + kq];
#pragma unroll
    for (int n = 0; n < 2; ++n)
      bfr[n] = *(const bf16x8*)&sB[(wc + n * 16 + rl) * 32 + kq];
#pragma unroll
    for (int m = 0; m < 4; ++m)
#pragma unroll
      for (int n = 0; n < 2; ++n)
        acc[m][n] = __builtin_amdgcn_mfma_f32_16x16x32_bf16(af[m], bfr[n], acc[m][n], 0, 0, 0);
  }
#pragma unroll
  for (int m = 0; m < 4; ++m) {
#pragma unroll
    for (int n = 0; n < 2; ++n) {
#pragma unroll
      for (int r = 0; r < 4; ++r) {
        int gm = m0 + m * 16 + hi * 4 + r;
        int gn = n0 + wc + n * 16 + rl;
        out[(size_t)gm * D_ + gn] = acc[m][n][r] + bo[gn];
      }
    }
  }
}

// ---------------- MFMA local causal attention: Q direct from global, 39KB LDS ----
#define QB 64
#define KW 112
#define KLP 68
#define VTP 116

__global__ __launch_bounds__(256) void k_attn(const bf16_t* __restrict__ Q,
                                              const bf16_t* __restrict__ K,
                                              const bf16_t* __restrict__ Vt,
                                              bf16_t* __restrict__ O) {
  __shared__ bf16_t sK[KW][KLP];
  __shared__ bf16_t sV[HD_][VTP];
  __shared__ bf16_t sP[4][16][KLP];
  int bid = blockIdx.x;
  int qb = bid & 31, bh = bid >> 5;
  int q0 = qb * QB;
  const bf16_t* Kp = K + (size_t)bh * S_ * HD_;
  const bf16_t* Vp = Vt + (size_t)bh * HD_ * S_;
  const bf16_t* Qp = Q + (size_t)bh * S_ * HD_;
  int tid = threadIdx.x;
  int lane = tid & 63, wave = tid >> 6;
  int rl = lane & 15, hi = lane >> 4;
  int wk0b = q0 - HW;
  bf16x8 qf0 = *(const bf16x8*)(Qp + (size_t)(q0 + wave * 16 + rl) * HD_ + hi * 8);
  bf16x8 qf1 = *(const bf16x8*)(Qp + (size_t)(q0 + wave * 16 + rl) * HD_ + 32 + hi * 8);
  for (int idx = tid; idx < KW * 8; idx += 256) {
    int row = idx >> 3, c8 = (idx & 7) * 8;
    int kg = wk0b + row;
    kg = kg < 0 ? 0 : (kg > S_ - 1 ? S_ - 1 : kg);
    *(bf16x8*)&sK[row][c8] = *(const bf16x8*)(Kp + (size_t)kg * HD_ + c8);
  }
  for (int idx = tid; idx < HD_ * 14; idx += 256) {
    int row = idx / 14, c8 = (idx % 14) * 8;
    int ks = wk0b + c8;
    ks = ks < 0 ? 0 : (ks > S_ - 8 ? S_ - 8 : ks);
    *(bf16x8*)&sV[row][c8] = *(const bf16x8*)(Vp + (size_t)row * S_ + ks);
  }
  __syncthreads();
  int wko = wave * 16;
  f32x4 accs[4] = {};
#pragma unroll
  for (int kb = 0; kb < 4; ++kb) {
    bf16x8 kf = *(const bf16x8*)&sK[wko + kb * 16 + rl][hi * 8];
    accs[kb] = __builtin_amdgcn_mfma_f32_16x16x32_bf16(kf, qf0, accs[kb], 0, 0, 0);
  }
#pragma unroll
  for (int kb = 0; kb < 4; ++kb) {
    bf16x8 kf = *(const bf16x8*)&sK[wko + kb * 16 + rl][32 + hi * 8];
    accs[kb] = __builtin_amdgcn_mfma_f32_16x16x32_bf16(kf, qf1, accs[kb], 0, 0, 0);
  }
  float p[4][4];
  float mx = -1e30f;
#pragma unroll
  for (int kb = 0; kb < 4; ++kb) {
#pragma unroll
    for (int r = 0; r < 4; ++r) {
      int kl = kb * 16 + hi * 4 + r;
      bool valid = (kl >= rl) && (kl <= rl + HW) && (wk0b + wko + kl >= 0);
      float s = valid ? accs[kb][r] : -1e30f;
      p[kb][r] = s;
      mx = fmaxf(mx, s);
    }
  }
  mx = fmaxf(mx, __shfl_xor(mx, 16));
  mx = fmaxf(mx, __shfl_xor(mx, 32));
  float sum = 0.f;
#pragma unroll
  for (int kb = 0; kb < 4; ++kb)
#pragma unroll
    for (int r = 0; r < 4; ++r) {
      p[kb][r] = __expf(p[kb][r] - mx);
      sum += p[kb][r];
    }
  sum += __shfl_xor(sum, 16);
  sum += __shfl_xor(sum, 32);
  float inv = 1.f / sum;
#pragma unroll
  for (int kb = 0; kb < 4; ++kb) {
    bf16x4 pv;
#pragma unroll
    for (int r = 0; r < 4; ++r) pv[r] = (bf16_t)(p[kb][r] * inv);
    *(bf16x4*)&sP[wave][rl][kb * 16 + hi * 4] = pv;
  }
  f32x4 acco[4] = {};
#pragma unroll
  for (int ks = 0; ks < 2; ++ks) {
    bf16x8 aP = *(const bf16x8*)&sP[wave][rl][ks * 32 + hi * 8];
#pragma unroll
    for (int n = 0; n < 4; ++n) {
      bf16x8 bV = *(const bf16x8*)&sV[n * 16 + rl][wko + ks * 32 + hi * 8];
      acco[n] = __builtin_amdgcn_mfma_f32_16x16x32_bf16(aP, bV, acco[n], 0, 0, 0);
    }
  }
  int b = bh >> 4, h = bh & 15;
#pragma unroll
  for (int n = 0; n < 4; ++n) {
#pragma unroll
    for (int r = 0; r < 4; ++r) {
      int qgl = q0 + wave * 16 + hi * 4 + r;
      int d = n * 16 + rl;
      O[((size_t)(b * S_ + qgl)) * D_ + h * HD_ + d] = (bf16_t)acco[n][r];
    }
  }
}

extern "C" void kernel_launch(void* const* d_in, const int* in_sizes, int n_in,
                              void* d_out, int out_size, void* d_ws, size_t ws_size,
                              hipStream_t stream) {
  const float* x  = (const float*)d_in[0];
  const float* Wq = (const float*)d_in[1];
  const float* Wk = (const float*)d_in[2];
  const float* Wv = (const float*)d_in[3];
  const float* Wo = (const float*)d_in[4];
  const float* bo = (const float*)d_in[5];
  float* out = (float*)d_out;
  char* ws = (char*)d_ws;
  bf16_t* xb = (bf16_t*)(ws);                       // 8 MB
  bf16_t* wt = (bf16_t*)(ws + (size_t)(8 << 20));   // 8 MB [4][1024][1024]
  bf16_t* qb = (bf16_t*)(ws + (size_t)(16 << 20));  // 8 MB [bh][s][64]
  bf16_t* kb = (bf16_t*)(ws + (size_t)(24 << 20));  // 8 MB [bh][s][64]
  bf16_t* vb = (bf16_t*)(ws + (size_t)(32 << 20));  // 8 MB [bh][64][s] (transposed)
  bf16_t* ob = (bf16_t*)(ws + (size_t)(40 << 20));  // 8 MB [b][s][1024]

  hipLaunchKernelGGL(k_conv, dim3(3072), dim3(256), 0, stream,
                     x, Wq, Wk, Wv, Wo, xb, wt);
  hipLaunchKernelGGL(k_gemm_qkv, dim3(768), dim3(256), 0, stream, xb, wt, qb, kb, vb);
  hipLaunchKernelGGL(k_attn, dim3(1024), dim3(256), 0, stream, qb, kb, vb, ob);
  hipLaunchKernelGGL(k_gemm_out, dim3(512), dim3(256), 0, stream,
                     ob, wt + (size_t)3 * D_ * D_, bo, out);
}